// Round 1
// baseline (1520.537 us; speedup 1.0000x reference)
//
#include <hip/hip_runtime.h>

#define N_NODES 100000
#define N_EDGES 3200000
#define D 128
#define K 8

#define WAVES_PER_BLOCK 4
#define NODES_PER_WAVE 32
#define NODES_PER_BLOCK (WAVES_PER_BLOCK * NODES_PER_WAVE)  // 128

// Phase 1: per (node, head) compute
//   t[n,k]    = relu(x[n] @ Ww_k) . Wm_k     (scalar, fp64 accum)
//   base[n,k] = x[n] . Wm_k                  (scalar, fp64 accum)
// for masked nodes; zeros otherwise (t MUST be 0 for unmasked src nodes).
// Block = one head x 128 nodes. Ww_k staged in LDS (64 KB -> 2 blocks/CU).
// One wave per node; lane l owns output columns l and l+64 (2-way bank
// aliasing on LDS is free). x row is wave-uniform -> scalar loads.
__global__ __launch_bounds__(256, 2)
void head_scores_kernel(const float* __restrict__ x,
                        const float* __restrict__ mask,
                        const float* __restrict__ Ww,
                        const float* __restrict__ Wm,
                        double* __restrict__ t,
                        double* __restrict__ base)
{
    __shared__ float ldsW[D * D];  // 64 KB
    const int k = blockIdx.y;

    // stage Ww[k] into LDS, coalesced float4
    {
        const float4* src = (const float4*)(Ww + (size_t)k * D * D);
        float4* dst = (float4*)ldsW;
        for (int i = threadIdx.x; i < (D * D) / 4; i += 256) dst[i] = src[i];
    }
    __syncthreads();

    const int lane = threadIdx.x & 63;
    const int wave = __builtin_amdgcn_readfirstlane((int)(threadIdx.x >> 6));

    // per-lane Wm fragment (columns l, l+64), promoted to fp64 once
    const double wm0 = (double)Wm[k * D + lane];
    const double wm1 = (double)Wm[k * D + lane + 64];

    const int nodeBase = blockIdx.x * NODES_PER_BLOCK + wave * NODES_PER_WAVE;
    for (int m = 0; m < NODES_PER_WAVE; ++m) {
        int n = nodeBase + m;
        if (n >= N_NODES) break;
        n = __builtin_amdgcn_readfirstlane(n);

        const float mval = mask[(size_t)n * K + k];
        if (!(mval > 0.0f)) {
            if (lane == 0) {
                t[(size_t)n * K + k] = 0.0;
                base[(size_t)n * K + k] = 0.0;
            }
            continue;
        }

        const float* xr = x + (size_t)n * D;
        double c0 = 0.0, c1 = 0.0;
        #pragma unroll 8
        for (int j = 0; j < D; ++j) {
            const double xd = (double)xr[j];          // wave-uniform -> s_load
            const float w0 = ldsW[j * D + lane];
            const float w1 = ldsW[j * D + lane + 64];
            c0 = fma(xd, (double)w0, c0);
            c1 = fma(xd, (double)w1, c1);
        }

        // per-lane partials
        double ts = fmax(c0, 0.0) * wm0 + fmax(c1, 0.0) * wm1;
        double bs = (double)xr[lane] * wm0 + (double)xr[lane + 64] * wm1;

        // 64-lane butterfly reduction
        #pragma unroll
        for (int off = 32; off > 0; off >>= 1) {
            ts += __shfl_xor(ts, off);
            bs += __shfl_xor(bs, off);
        }
        if (lane == 0) {
            t[(size_t)n * K + k] = ts;
            base[(size_t)n * K + k] = bs;
        }
    }
}

// Phase 2: agg[dst,k] += t[src,k] over all edges. t==0 encodes "src not in
// this head's mask" (and zero-t contributions), so no mask read needed here;
// dst-mask gating happens in phase 3. Thread per (edge, head): lanes in
// groups of 8 coalesce the 64 B t[src,0..7] read.
__global__ __launch_bounds__(256)
void scatter_kernel(const int* __restrict__ ei,
                    const double* __restrict__ t,
                    double* __restrict__ agg)
{
    const long long tid = (long long)blockIdx.x * 256 + threadIdx.x;
    if (tid >= (long long)N_EDGES * K) return;
    const int k = (int)(tid & (K - 1));
    const long long e = tid >> 3;
    const int s = ei[e];
    const int d = ei[(long long)N_EDGES + e];
    const double v = t[(size_t)s * K + k];
    if (v != 0.0) atomicAdd(&agg[(size_t)d * K + k], v);
}

// Phase 3: head boolean = (mask>0) && (base+agg > 0)  [== tanh(score)>0].
// top_k(norms masked, 2) with all-equal finite values + lax.top_k's
// lowest-index tie-break == "first <=2 true heads by index".
__global__ __launch_bounds__(256)
void combine_kernel(const float* __restrict__ mask,
                    const double* __restrict__ base,
                    const double* __restrict__ agg,
                    float* __restrict__ out)
{
    const int n = blockIdx.x * 256 + threadIdx.x;
    if (n >= N_NODES) return;
    float o[K];
    int cnt = 0;
    #pragma unroll
    for (int k = 0; k < K; ++k) {
        const bool hm = (mask[(size_t)n * K + k] > 0.0f) &&
                        ((base[(size_t)n * K + k] + agg[(size_t)n * K + k]) > 0.0);
        o[k] = (hm && cnt < 2) ? 1.0f : 0.0f;
        cnt += hm ? 1 : 0;
    }
    float4* op = (float4*)(out + (size_t)n * K);
    op[0] = make_float4(o[0], o[1], o[2], o[3]);
    op[1] = make_float4(o[4], o[5], o[6], o[7]);
}

extern "C" void kernel_launch(void* const* d_in, const int* in_sizes, int n_in,
                              void* d_out, int out_size, void* d_ws, size_t ws_size,
                              hipStream_t stream)
{
    const float* x    = (const float*)d_in[0];
    const int*   ei   = (const int*)d_in[1];   // edge_index [2, E] int32
    const float* mask = (const float*)d_in[2]; // [N, K]
    const float* Ww   = (const float*)d_in[3]; // [K, D, D]
    const float* Wm   = (const float*)d_in[4]; // [K, D, 1]
    float* out = (float*)d_out;                // [N, K] float32

    // workspace layout: t | base | agg, each N*K doubles (3 x 6.4 MB)
    double* t    = (double*)d_ws;
    double* base = t + (size_t)N_NODES * K;
    double* agg  = base + (size_t)N_NODES * K;

    hipMemsetAsync(agg, 0, (size_t)N_NODES * K * sizeof(double), stream);

    dim3 g1((N_NODES + NODES_PER_BLOCK - 1) / NODES_PER_BLOCK, K);
    head_scores_kernel<<<g1, 256, 0, stream>>>(x, mask, Ww, Wm, t, base);

    const long long nek = (long long)N_EDGES * K;
    scatter_kernel<<<(int)((nek + 255) / 256), 256, 0, stream>>>(ei, t, agg);

    combine_kernel<<<(N_NODES + 255) / 256, 256, 0, stream>>>(mask, base, agg, out);
}

// Round 2
// 938.983 us; speedup vs baseline: 1.6193x; 1.6193x over previous
//
#include <hip/hip_runtime.h>

#define N_NODES 100000
#define N_EDGES 3200000
#define D 128
#define K 8

#define WAVES_PER_BLOCK 4
#define NODES_PER_WAVE 64
#define NODES_PER_BLOCK (WAVES_PER_BLOCK * NODES_PER_WAVE)  // 256

// Phase 1: per masked (node, head) compute (fp64-exact accumulation):
//   t[n,k]    = relu(x[n] @ Ww_k) . Wm_k
//   base[n,k] = x[n] . Wm_k
// t for unmasked nodes is pre-zeroed by memset (scatter reads t for all edges).
//
// Block = one head x 256 nodes (4 waves x 64). Ww_k staged in LDS as fp32
// (64 KB -> 2 blocks/CU). Each wave ballots its 64 nodes' mask bits and
// processes masked nodes in groups of 8, giving 16 independent fp64 FMA
// chains (ILP covers dfma latency at 2 waves/SIMD) and amortizing the
// Ww fp32->fp64 cvt 8x. Lane l owns output columns l and l+64 (2-way LDS
// bank aliasing is free). x reads are wave-uniform -> scalar loads.
__global__ __launch_bounds__(256, 2)
void head_scores_kernel(const float* __restrict__ x,
                        const float* __restrict__ mask,
                        const float* __restrict__ Ww,
                        const float* __restrict__ Wm,
                        double* __restrict__ t,
                        double* __restrict__ base)
{
    __shared__ float ldsW[D * D];  // 64 KB
    const int k = blockIdx.y;

    // stage Ww[k] into LDS, coalesced float4
    {
        const float4* src = (const float4*)(Ww + (size_t)k * D * D);
        float4* dst = (float4*)ldsW;
        #pragma unroll
        for (int i = 0; i < (D * D) / 4 / 256; ++i)
            dst[i * 256 + threadIdx.x] = src[i * 256 + threadIdx.x];
    }
    __syncthreads();

    const int lane = threadIdx.x & 63;
    const int wave = __builtin_amdgcn_readfirstlane((int)(threadIdx.x >> 6));

    // per-lane Wm fragment (columns l, l+64), promoted to fp64 once
    const double wm0 = (double)Wm[k * D + lane];
    const double wm1 = (double)Wm[k * D + lane + 64];

    const int nodeBase = (blockIdx.x * WAVES_PER_BLOCK + wave) * NODES_PER_WAVE;

    // ballot the 64 nodes' mask bits for this head
    const int myNode = nodeBase + lane;
    const float mv = (myNode < N_NODES) ? mask[(size_t)myNode * K + k] : 0.0f;
    unsigned long long bits = __ballot(mv > 0.0f);

    while (bits) {
        // extract up to 8 set bits (wave-uniform scalar work)
        int cnt = __popcll(bits);
        if (cnt > 8) cnt = 8;
        const int first = nodeBase + (__ffsll((long long)bits) - 1);
        int ids[8];
        #pragma unroll
        for (int i = 0; i < 8; ++i) {
            const int b = __ffsll((long long)bits);
            ids[i] = (b != 0) ? (nodeBase + b - 1) : first;
            if (b != 0) bits &= (bits - 1);
        }

        const float* xr[8];
        #pragma unroll
        for (int i = 0; i < 8; ++i) xr[i] = x + (size_t)ids[i] * D;

        double a0[8], a1[8];
        #pragma unroll
        for (int i = 0; i < 8; ++i) { a0[i] = 0.0; a1[i] = 0.0; }

        #pragma unroll 4
        for (int j = 0; j < D; ++j) {
            const double dw0 = (double)ldsW[j * D + lane];
            const double dw1 = (double)ldsW[j * D + lane + 64];
            #pragma unroll
            for (int i = 0; i < 8; ++i) {
                const double xd = (double)xr[i][j];  // wave-uniform -> s_load
                a0[i] = fma(xd, dw0, a0[i]);
                a1[i] = fma(xd, dw1, a1[i]);
            }
        }

        #pragma unroll
        for (int i = 0; i < 8; ++i) {
            if (i >= cnt) break;
            double ts = fmax(a0[i], 0.0) * wm0 + fmax(a1[i], 0.0) * wm1;
            double bs = (double)xr[i][lane] * wm0 + (double)xr[i][lane + 64] * wm1;
            // 64-lane butterfly reduction
            #pragma unroll
            for (int off = 32; off > 0; off >>= 1) {
                ts += __shfl_xor(ts, off);
                bs += __shfl_xor(bs, off);
            }
            if (lane == 0) {
                t[(size_t)ids[i] * K + k] = ts;
                base[(size_t)ids[i] * K + k] = bs;
            }
        }
    }
}

// Phase 2: agg[dst,k] += t[src,k] over all edges. t==0 encodes "src not in
// this head's mask" (zeros pre-set by memset), so no mask read needed here;
// dst-mask gating happens in phase 3. Thread per (edge, head): lanes in
// groups of 8 coalesce the 64 B t[src,0..7] read.
__global__ __launch_bounds__(256)
void scatter_kernel(const int* __restrict__ ei,
                    const double* __restrict__ t,
                    double* __restrict__ agg)
{
    const long long tid = (long long)blockIdx.x * 256 + threadIdx.x;
    if (tid >= (long long)N_EDGES * K) return;
    const int k = (int)(tid & (K - 1));
    const long long e = tid >> 3;
    const int s = ei[e];
    const int d = ei[(long long)N_EDGES + e];
    const double v = t[(size_t)s * K + k];
    if (v != 0.0) atomicAdd(&agg[(size_t)d * K + k], v);
}

// Phase 3: head boolean = (mask>0) && (base+agg > 0)  [== tanh(score)>0].
// top_k(norms masked, 2) with all-equal finite values + lax.top_k's
// lowest-index tie-break == "first <=2 true heads by index".
__global__ __launch_bounds__(256)
void combine_kernel(const float* __restrict__ mask,
                    const double* __restrict__ base,
                    const double* __restrict__ agg,
                    float* __restrict__ out)
{
    const int n = blockIdx.x * 256 + threadIdx.x;
    if (n >= N_NODES) return;
    float o[K];
    int cnt = 0;
    #pragma unroll
    for (int k = 0; k < K; ++k) {
        const bool hm = (mask[(size_t)n * K + k] > 0.0f) &&
                        ((base[(size_t)n * K + k] + agg[(size_t)n * K + k]) > 0.0);
        o[k] = (hm && cnt < 2) ? 1.0f : 0.0f;
        cnt += hm ? 1 : 0;
    }
    float4* op = (float4*)(out + (size_t)n * K);
    op[0] = make_float4(o[0], o[1], o[2], o[3]);
    op[1] = make_float4(o[4], o[5], o[6], o[7]);
}

extern "C" void kernel_launch(void* const* d_in, const int* in_sizes, int n_in,
                              void* d_out, int out_size, void* d_ws, size_t ws_size,
                              hipStream_t stream)
{
    const float* x    = (const float*)d_in[0];
    const int*   ei   = (const int*)d_in[1];   // edge_index [2, E] int32
    const float* mask = (const float*)d_in[2]; // [N, K]
    const float* Ww   = (const float*)d_in[3]; // [K, D, D]
    const float* Wm   = (const float*)d_in[4]; // [K, D, 1]
    float* out = (float*)d_out;                // [N, K] float32

    // workspace layout: t | base | agg, each N*K doubles (3 x 6.4 MB)
    double* t    = (double*)d_ws;
    double* base = t + (size_t)N_NODES * K;
    double* agg  = base + (size_t)N_NODES * K;

    // t must be zero for unmasked (n,k); agg accumulates.
    hipMemsetAsync(t, 0, (size_t)N_NODES * K * sizeof(double), stream);
    hipMemsetAsync(agg, 0, (size_t)N_NODES * K * sizeof(double), stream);

    dim3 g1((N_NODES + NODES_PER_BLOCK - 1) / NODES_PER_BLOCK, K);
    head_scores_kernel<<<g1, 256, 0, stream>>>(x, mask, Ww, Wm, t, base);

    const long long nek = (long long)N_EDGES * K;
    scatter_kernel<<<(int)((nek + 255) / 256), 256, 0, stream>>>(ei, t, agg);

    combine_kernel<<<(N_NODES + 255) / 256, 256, 0, stream>>>(mask, base, agg, out);
}

// Round 3
// 908.220 us; speedup vs baseline: 1.6742x; 1.0339x over previous
//
#include <hip/hip_runtime.h>

#define N_NODES 100000
#define N_EDGES 3200000
#define D 128
#define K 8

#define WAVES_PER_BLOCK 4
#define NODES_PER_WAVE 64
#define NODES_PER_BLOCK (WAVES_PER_BLOCK * NODES_PER_WAVE)  // 256

// |score32| below this => exact fp64 repair. fp32 score error sigma ~1e-5,
// so 2e-3 is ~200 sigma: no sign flip can survive unflagged.
#define TAU 2e-3f
#define WL_CAP 262144  // repair worklist capacity (~40x expected max)

// ---------------------------------------------------------------------------
// Phase 1 (fp32): per masked (node, head):
//   t32[n,k]    = relu(x[n] @ Ww_k) . Wm_k
//   base32[n,k] = x[n] . Wm_k
// t32 for unmasked (n,k) pre-zeroed by memset (scatter reads all edges).
// Block = one head x 256 nodes (4 waves x 64). Ww_k in LDS (64 KB).
// Wave ballots its 64 nodes' mask bits, processes masked nodes in groups of
// 8 -> 16 independent f32 fmac chains. Group ids are readfirstlane'd so the
// x-row loads become SMEM scalar loads (v_fmac_f32 v, s, v).
// ---------------------------------------------------------------------------
__global__ __launch_bounds__(256, 2)
void head_scores_kernel(const float* __restrict__ x,
                        const float* __restrict__ mask,
                        const float* __restrict__ Ww,
                        const float* __restrict__ Wm,
                        float* __restrict__ t32,
                        float* __restrict__ base32)
{
    __shared__ float ldsW[D * D];  // 64 KB
    const int k = blockIdx.y;

    {
        const float4* src = (const float4*)(Ww + (size_t)k * D * D);
        float4* dst = (float4*)ldsW;
        #pragma unroll
        for (int i = 0; i < (D * D) / 4 / 256; ++i)
            dst[i * 256 + threadIdx.x] = src[i * 256 + threadIdx.x];
    }
    __syncthreads();

    const int lane = threadIdx.x & 63;
    const int wave = __builtin_amdgcn_readfirstlane((int)(threadIdx.x >> 6));

    const float wm0 = Wm[k * D + lane];
    const float wm1 = Wm[k * D + lane + 64];

    const int nodeBase = (blockIdx.x * WAVES_PER_BLOCK + wave) * NODES_PER_WAVE;
    const int myNode = nodeBase + lane;
    const float mv = (myNode < N_NODES) ? mask[(size_t)myNode * K + k] : 0.0f;
    unsigned long long bits = __ballot(mv > 0.0f);

    while (bits) {
        int cnt = __popcll(bits);
        if (cnt > 8) cnt = 8;
        const int first = nodeBase + (__ffsll((long long)bits) - 1);
        int ids[8];
        #pragma unroll
        for (int i = 0; i < 8; ++i) {
            const int b = __ffsll((long long)bits);
            ids[i] = (b != 0) ? (nodeBase + b - 1) : first;
            if (b != 0) bits &= (bits - 1);
            ids[i] = __builtin_amdgcn_readfirstlane(ids[i]);  // -> SGPR
        }

        const float* xr[8];
        #pragma unroll
        for (int i = 0; i < 8; ++i) xr[i] = x + (size_t)ids[i] * D;

        float a0[8], a1[8];
        #pragma unroll
        for (int i = 0; i < 8; ++i) { a0[i] = 0.0f; a1[i] = 0.0f; }

        #pragma unroll 4
        for (int j = 0; j < D; ++j) {
            const float w0 = ldsW[j * D + lane];
            const float w1 = ldsW[j * D + lane + 64];
            #pragma unroll
            for (int i = 0; i < 8; ++i) {
                const float xd = xr[i][j];  // uniform addr -> s_load
                a0[i] = fmaf(xd, w0, a0[i]);
                a1[i] = fmaf(xd, w1, a1[i]);
            }
        }

        #pragma unroll
        for (int i = 0; i < 8; ++i) {
            if (i >= cnt) break;
            float ts = fmaxf(a0[i], 0.0f) * wm0 + fmaxf(a1[i], 0.0f) * wm1;
            float bs = xr[i][lane] * wm0 + xr[i][lane + 64] * wm1;
            #pragma unroll
            for (int off = 32; off > 0; off >>= 1) {
                ts += __shfl_xor(ts, off);
                bs += __shfl_xor(bs, off);
            }
            if (lane == 0) {
                t32[(size_t)ids[i] * K + k] = ts;
                base32[(size_t)ids[i] * K + k] = bs;
            }
        }
    }
}

// ---------------------------------------------------------------------------
// Phase 2 (fp32): agg32[dst,k] += t32[src,k]. t32==0 encodes unmasked src.
// Thread per (edge, head); 8 lanes share one edge -> coalesced 32 B t-row.
// ---------------------------------------------------------------------------
__global__ __launch_bounds__(256)
void scatter_kernel(const int* __restrict__ ei,
                    const float* __restrict__ t32,
                    float* __restrict__ agg32)
{
    const long long tid = (long long)blockIdx.x * 256 + threadIdx.x;
    if (tid >= (long long)N_EDGES * K) return;
    const int k = (int)(tid & (K - 1));
    const long long e = tid >> 3;
    const int s = ei[e];
    const int d = ei[(long long)N_EDGES + e];
    const float v = t32[(size_t)s * K + k];
    if (v != 0.0f) atomicAdd(&agg32[(size_t)d * K + k], v);
}

// ---------------------------------------------------------------------------
// Phase 3: tentative combine + flag near-zero scores for exact repair.
// head bool = (mask>0) && (score>0); output = first <=2 true heads (lax.top_k
// on all-equal norms tie-breaks by lowest index).
// ---------------------------------------------------------------------------
__global__ __launch_bounds__(256)
void combine_flag_kernel(const float* __restrict__ mask,
                         const float* __restrict__ base32,
                         const float* __restrict__ agg32,
                         float* __restrict__ out,
                         unsigned char* __restrict__ flag8)
{
    const int n = blockIdx.x * 256 + threadIdx.x;
    if (n >= N_NODES) return;
    float o[K];
    int cnt = 0, fl = 0;
    #pragma unroll
    for (int k = 0; k < K; ++k) {
        const float m = mask[(size_t)n * K + k];
        const float s = base32[(size_t)n * K + k] + agg32[(size_t)n * K + k];
        const bool masked = (m > 0.0f);
        const bool hm = masked && (s > 0.0f);
        if (masked && fabsf(s) < TAU) fl |= (1 << k);
        o[k] = (hm && cnt < 2) ? 1.0f : 0.0f;
        cnt += hm ? 1 : 0;
    }
    float4* op = (float4*)(out + (size_t)n * K);
    op[0] = make_float4(o[0], o[1], o[2], o[3]);
    op[1] = make_float4(o[4], o[5], o[6], o[7]);
    flag8[n] = (unsigned char)fl;
}

// ---------------------------------------------------------------------------
// Repair A: scan edges; for edges into flagged (dst,k) with masked src,
// append (src,k,dst) to worklist.
// ---------------------------------------------------------------------------
__global__ __launch_bounds__(256)
void edge_flag_kernel(const int* __restrict__ ei,
                      const float* __restrict__ mask,
                      const unsigned char* __restrict__ flag8,
                      int2* __restrict__ wl,
                      int* __restrict__ wlcnt)
{
    const int e = blockIdx.x * 256 + threadIdx.x;
    if (e >= N_EDGES) return;
    const int d = ei[(long long)N_EDGES + e];
    unsigned f = flag8[d];
    if (!f) return;
    const int s = ei[e];
    while (f) {
        const int k = __ffs(f) - 1;
        f &= f - 1;
        if (mask[(size_t)s * K + k] > 0.0f) {
            const int idx = atomicAdd(wlcnt, 1);
            if (idx < WL_CAP) wl[idx] = make_int2(s | (k << 20), d);
        }
    }
}

// ---------------------------------------------------------------------------
// Repair B: one wave per worklist entry: t64 = relu64(x@Ww_k).Wm_k exactly,
// atomicAdd into score64[dst,k]. Grid-stride; count read from ws.
// ---------------------------------------------------------------------------
__global__ __launch_bounds__(256)
void repair_t_kernel(const float* __restrict__ x,
                     const float* __restrict__ Ww,
                     const float* __restrict__ Wm,
                     const int2* __restrict__ wl,
                     const int* __restrict__ wlcnt,
                     double* __restrict__ score64)
{
    const int lane = threadIdx.x & 63;
    const int waveId = blockIdx.x * 4 + (threadIdx.x >> 6);
    const int nWaves = gridDim.x * 4;
    int cnt = *wlcnt;
    if (cnt > WL_CAP) cnt = WL_CAP;
    for (int w = waveId; w < cnt; w += nWaves) {
        const int2 ent = wl[w];
        const int s = __builtin_amdgcn_readfirstlane(ent.x & 0xFFFFF);
        const int k = __builtin_amdgcn_readfirstlane(ent.x >> 20);
        const int d = ent.y;
        const float* xr = x + (size_t)s * D;
        const float* Wk = Ww + (size_t)k * D * D;
        double c0 = 0.0, c1 = 0.0;
        for (int j = 0; j < D; ++j) {
            const double xd = (double)xr[j];
            c0 = fma(xd, (double)Wk[j * D + lane], c0);
            c1 = fma(xd, (double)Wk[j * D + lane + 64], c1);
        }
        double ts = fmax(c0, 0.0) * (double)Wm[k * D + lane]
                  + fmax(c1, 0.0) * (double)Wm[k * D + lane + 64];
        #pragma unroll
        for (int off = 32; off > 0; off >>= 1) ts += __shfl_xor(ts, off);
        if (lane == 0) atomicAdd(&score64[(size_t)d * K + k], ts);
    }
}

// ---------------------------------------------------------------------------
// Repair C: for flagged nodes, recompute flagged heads exactly
// (base64 + aggregated t64) and rewrite the output row.
// ---------------------------------------------------------------------------
__global__ __launch_bounds__(256)
void repair_combine_kernel(const float* __restrict__ x,
                           const float* __restrict__ mask,
                           const float* __restrict__ Wm,
                           const float* __restrict__ base32,
                           const float* __restrict__ agg32,
                           const double* __restrict__ score64,
                           const unsigned char* __restrict__ flag8,
                           float* __restrict__ out)
{
    const int n = blockIdx.x * 256 + threadIdx.x;
    if (n >= N_NODES) return;
    const unsigned f = flag8[n];
    if (!f) return;
    float o[K];
    int cnt = 0;
    #pragma unroll
    for (int k = 0; k < K; ++k) {
        const float m = mask[(size_t)n * K + k];
        bool hm;
        if ((f >> k) & 1) {
            double b = 0.0;
            for (int j = 0; j < D; ++j)
                b = fma((double)x[(size_t)n * D + j], (double)Wm[k * D + j], b);
            hm = (b + score64[(size_t)n * K + k]) > 0.0;
        } else {
            hm = (m > 0.0f) &&
                 ((base32[(size_t)n * K + k] + agg32[(size_t)n * K + k]) > 0.0f);
        }
        o[k] = (hm && cnt < 2) ? 1.0f : 0.0f;
        cnt += hm ? 1 : 0;
    }
    float4* op = (float4*)(out + (size_t)n * K);
    op[0] = make_float4(o[0], o[1], o[2], o[3]);
    op[1] = make_float4(o[4], o[5], o[6], o[7]);
}

extern "C" void kernel_launch(void* const* d_in, const int* in_sizes, int n_in,
                              void* d_out, int out_size, void* d_ws, size_t ws_size,
                              hipStream_t stream)
{
    const float* x    = (const float*)d_in[0];
    const int*   ei   = (const int*)d_in[1];   // edge_index [2, E] int32
    const float* mask = (const float*)d_in[2]; // [N, K]
    const float* Ww   = (const float*)d_in[3]; // [K, D, D]
    const float* Wm   = (const float*)d_in[4]; // [K, D, 1]
    float* out = (float*)d_out;                // [N, K] float32

    // workspace layout (all offsets 8-aligned where needed):
    //   [0, 3.2M)        t32      f32[N*K]
    //   [3.2M, 6.4M)     agg32    f32[N*K]
    //   [6.4M, 12.8M)    score64  f64[N*K]
    //   [12.8M, 12.9M)   flag8    u8[N]
    //   [12.9M, +8)      wlcnt    int (+pad)
    //   [+8, +8+2M)      wl       int2[WL_CAP]
    //   [..., +3.2M)     base32   f32[N*K]
    char* w = (char*)d_ws;
    float*         t32    = (float*)w;
    float*         agg32  = (float*)(w + 3200000);
    double*        s64    = (double*)(w + 6400000);
    unsigned char* flag8  = (unsigned char*)(w + 12800000);
    int*           wlcnt  = (int*)(w + 12900000);
    int2*          wl     = (int2*)(w + 12900008);
    float*         b32    = (float*)(w + 12900008 + (size_t)WL_CAP * 8);

    // one contiguous zero region: t32 | agg32 | score64 | flag8 | wlcnt
    hipMemsetAsync(w, 0, 12900008, stream);

    dim3 g1((N_NODES + NODES_PER_BLOCK - 1) / NODES_PER_BLOCK, K);
    head_scores_kernel<<<g1, 256, 0, stream>>>(x, mask, Ww, Wm, t32, b32);

    const long long nek = (long long)N_EDGES * K;
    scatter_kernel<<<(int)((nek + 255) / 256), 256, 0, stream>>>(ei, t32, agg32);

    combine_flag_kernel<<<(N_NODES + 255) / 256, 256, 0, stream>>>(
        mask, b32, agg32, out, flag8);

    edge_flag_kernel<<<(N_EDGES + 255) / 256, 256, 0, stream>>>(
        ei, mask, flag8, wl, wlcnt);

    repair_t_kernel<<<512, 256, 0, stream>>>(x, Ww, Wm, wl, wlcnt, s64);

    repair_combine_kernel<<<(N_NODES + 255) / 256, 256, 0, stream>>>(
        x, mask, Wm, b32, agg32, s64, flag8, out);
}

// Round 4
// 694.968 us; speedup vs baseline: 2.1879x; 1.3069x over previous
//
#include <hip/hip_runtime.h>

#define N_NODES 100000
#define N_EDGES 3200000
#define D 128
#define K 8

// |score32| below this => exact fp64 repair. fp32 score error sigma ~1e-5,
// so 2e-3 is ~200 sigma: no sign flip can survive unflagged.
#define TAU 2e-3f
#define WL_CAP 262144  // repair worklist capacity

#define CHUNK 64   // nodes per head_gemm block
#define CCH   32   // output columns per wave

// ---------------------------------------------------------------------------
// Phase 0: per-head compaction of masked node ids.
// lists[k][0..cnts[k]) = node ids with mask[n,k] > 0 (order irrelevant).
// One ballot + one atomic per wave per head.
// ---------------------------------------------------------------------------
__global__ __launch_bounds__(256)
void compact_kernel(const float* __restrict__ mask,
                    int* __restrict__ lists,
                    int* __restrict__ cnts)
{
    const int n = blockIdx.x * 256 + threadIdx.x;
    const int lane = threadIdx.x & 63;
    const bool valid = (n < N_NODES);
    #pragma unroll
    for (int k = 0; k < K; ++k) {
        const bool m = valid && (mask[(size_t)n * K + k] > 0.0f);
        const unsigned long long b = __ballot(m);
        const int cw = __popcll(b);
        int base = 0;
        if (lane == 0 && cw) base = atomicAdd(&cnts[k], cw);
        base = __shfl(base, 0);
        if (m) {
            const int pos = __popcll(b & ((1ull << lane) - 1ull));
            lists[(size_t)k * N_NODES + base + pos] = n;
        }
    }
}

// ---------------------------------------------------------------------------
// Phase 1 (fp32): for each compacted (node,head):
//   t32[n,k]    = relu(x[n] @ Ww_k) . Wm_k
//   base32[n,k] = x[n] . Wm_k
// Block = 64 nodes x 1 head. xT staged transposed in LDS (pad 65 -> all LDS
// accesses conflict-free at worst 2-way). Lane = node; wave w owns output
// columns [32w, 32w+32): per j one ds_read_b32 (x, per-lane) + 32 fmacs with
// wave-uniform W row chunk (s_load_dwordx16 batched). 33 KB LDS ->
// 4 blocks/CU = 16 waves/CU.
// ---------------------------------------------------------------------------
__global__ __launch_bounds__(256)
void head_gemm_kernel(const float* __restrict__ x,
                      const float* __restrict__ Ww,
                      const float* __restrict__ Wm,
                      const int* __restrict__ lists,
                      const int* __restrict__ cnts,
                      float* __restrict__ t32,
                      float* __restrict__ base32)
{
    __shared__ float xT[D][CHUNK + 1];   // 33.3 KB
    __shared__ float redT[4][CHUNK];
    __shared__ float redB[4][CHUNK];

    const int k = blockIdx.y;
    const int cnt = cnts[k];
    const int nbase = blockIdx.x * CHUNK;
    if (nbase >= cnt) return;            // block-uniform exit (before barriers)

    const int lane = threadIdx.x & 63;
    const int wave = __builtin_amdgcn_readfirstlane((int)(threadIdx.x >> 6));
    const int* list = lists + (size_t)k * N_NODES;

    // stage 16 rows per wave, transposed; clamp tail (duplicate rows harmless)
    #pragma unroll
    for (int i = 0; i < 16; ++i) {
        const int r = wave * 16 + i;
        int idx = nbase + r;
        if (idx >= cnt) idx = cnt - 1;
        const int id = __builtin_amdgcn_readfirstlane(lists[(size_t)k * N_NODES + idx]);
        xT[lane][r]      = x[(size_t)id * D + lane];        // 256 B coalesced
        xT[lane + 64][r] = x[(size_t)id * D + lane + 64];
    }
    __syncthreads();

    const int c0 = wave * CCH;
    const float* Wk = Ww + (size_t)k * D * D + c0;

    float acc[CCH];
    #pragma unroll
    for (int c = 0; c < CCH; ++c) acc[c] = 0.0f;

    #pragma unroll 4
    for (int j = 0; j < D; ++j) {
        const float xv = xT[j][lane];          // conflict-free ds_read_b32
        const float* wr = Wk + j * D;          // wave-uniform -> s_load x16
        #pragma unroll
        for (int c = 0; c < CCH; ++c)
            acc[c] = fmaf(xv, wr[c], acc[c]);  // v_fmac_f32 v, s, v
    }

    // epilogue: per-lane partials for this column chunk
    float tp = 0.0f, bp = 0.0f;
    #pragma unroll 4
    for (int c = 0; c < CCH; ++c) {
        const float wm = Wm[k * D + c0 + c];   // wave-uniform s_load
        tp = fmaf(fmaxf(acc[c], 0.0f), wm, tp);
        bp = fmaf(xT[c0 + c][lane], wm, bp);
    }
    redT[wave][lane] = tp;
    redB[wave][lane] = bp;
    __syncthreads();

    if (wave == 0) {
        const int idx = nbase + lane;
        if (idx < cnt) {
            const int id = list[idx];
            t32[(size_t)id * K + k]    = redT[0][lane] + redT[1][lane] +
                                         redT[2][lane] + redT[3][lane];
            base32[(size_t)id * K + k] = redB[0][lane] + redB[1][lane] +
                                         redB[2][lane] + redB[3][lane];
        }
    }
}

// ---------------------------------------------------------------------------
// Phase 2 (fp32): agg32[dst,k] += t32[src,k]. t32==0 encodes unmasked src.
// Thread per (edge, head); 8 lanes share one edge -> coalesced 32 B t-row.
// ---------------------------------------------------------------------------
__global__ __launch_bounds__(256)
void scatter_kernel(const int* __restrict__ ei,
                    const float* __restrict__ t32,
                    float* __restrict__ agg32)
{
    const long long tid = (long long)blockIdx.x * 256 + threadIdx.x;
    if (tid >= (long long)N_EDGES * K) return;
    const int k = (int)(tid & (K - 1));
    const long long e = tid >> 3;
    const int s = ei[e];
    const int d = ei[(long long)N_EDGES + e];
    const float v = t32[(size_t)s * K + k];
    if (v != 0.0f) atomicAdd(&agg32[(size_t)d * K + k], v);
}

// ---------------------------------------------------------------------------
// Phase 3: tentative combine + flag near-zero scores for exact repair.
// head bool = (mask>0) && (score>0); output = first <=2 true heads (lax.top_k
// on all-equal norms tie-breaks by lowest index).
// ---------------------------------------------------------------------------
__global__ __launch_bounds__(256)
void combine_flag_kernel(const float* __restrict__ mask,
                         const float* __restrict__ base32,
                         const float* __restrict__ agg32,
                         float* __restrict__ out,
                         unsigned char* __restrict__ flag8)
{
    const int n = blockIdx.x * 256 + threadIdx.x;
    if (n >= N_NODES) return;
    float o[K];
    int cnt = 0, fl = 0;
    #pragma unroll
    for (int k = 0; k < K; ++k) {
        const float m = mask[(size_t)n * K + k];
        const float s = base32[(size_t)n * K + k] + agg32[(size_t)n * K + k];
        const bool masked = (m > 0.0f);
        const bool hm = masked && (s > 0.0f);
        if (masked && fabsf(s) < TAU) fl |= (1 << k);
        o[k] = (hm && cnt < 2) ? 1.0f : 0.0f;
        cnt += hm ? 1 : 0;
    }
    float4* op = (float4*)(out + (size_t)n * K);
    op[0] = make_float4(o[0], o[1], o[2], o[3]);
    op[1] = make_float4(o[4], o[5], o[6], o[7]);
    flag8[n] = (unsigned char)fl;
}

// ---------------------------------------------------------------------------
// Repair A: edges into flagged (dst,k) with masked src -> worklist.
// ---------------------------------------------------------------------------
__global__ __launch_bounds__(256)
void edge_flag_kernel(const int* __restrict__ ei,
                      const float* __restrict__ mask,
                      const unsigned char* __restrict__ flag8,
                      int2* __restrict__ wl,
                      int* __restrict__ wlcnt)
{
    const int e = blockIdx.x * 256 + threadIdx.x;
    if (e >= N_EDGES) return;
    const int d = ei[(long long)N_EDGES + e];
    unsigned f = flag8[d];
    if (!f) return;
    const int s = ei[e];
    while (f) {
        const int k = __ffs(f) - 1;
        f &= f - 1;
        if (mask[(size_t)s * K + k] > 0.0f) {
            const int idx = atomicAdd(wlcnt, 1);
            if (idx < WL_CAP) wl[idx] = make_int2(s | (k << 20), d);
        }
    }
}

// ---------------------------------------------------------------------------
// Repair B: one wave per worklist entry: exact fp64 t, atomic into score64.
// ---------------------------------------------------------------------------
__global__ __launch_bounds__(256)
void repair_t_kernel(const float* __restrict__ x,
                     const float* __restrict__ Ww,
                     const float* __restrict__ Wm,
                     const int2* __restrict__ wl,
                     const int* __restrict__ wlcnt,
                     double* __restrict__ score64)
{
    const int lane = threadIdx.x & 63;
    const int waveId = blockIdx.x * 4 + (threadIdx.x >> 6);
    const int nWaves = gridDim.x * 4;
    int cnt = *wlcnt;
    if (cnt > WL_CAP) cnt = WL_CAP;
    for (int w = waveId; w < cnt; w += nWaves) {
        const int2 ent = wl[w];
        const int s = __builtin_amdgcn_readfirstlane(ent.x & 0xFFFFF);
        const int k = __builtin_amdgcn_readfirstlane(ent.x >> 20);
        const int d = ent.y;
        const float* xr = x + (size_t)s * D;
        const float* Wk = Ww + (size_t)k * D * D;
        double c0 = 0.0, c1 = 0.0;
        for (int j = 0; j < D; ++j) {
            const double xd = (double)xr[j];
            c0 = fma(xd, (double)Wk[j * D + lane], c0);
            c1 = fma(xd, (double)Wk[j * D + lane + 64], c1);
        }
        double ts = fmax(c0, 0.0) * (double)Wm[k * D + lane]
                  + fmax(c1, 0.0) * (double)Wm[k * D + lane + 64];
        #pragma unroll
        for (int off = 32; off > 0; off >>= 1) ts += __shfl_xor(ts, off);
        if (lane == 0) atomicAdd(&score64[(size_t)d * K + k], ts);
    }
}

// ---------------------------------------------------------------------------
// Repair C: rewrite output rows of flagged nodes using exact scores.
// ---------------------------------------------------------------------------
__global__ __launch_bounds__(256)
void repair_combine_kernel(const float* __restrict__ x,
                           const float* __restrict__ mask,
                           const float* __restrict__ Wm,
                           const float* __restrict__ base32,
                           const float* __restrict__ agg32,
                           const double* __restrict__ score64,
                           const unsigned char* __restrict__ flag8,
                           float* __restrict__ out)
{
    const int n = blockIdx.x * 256 + threadIdx.x;
    if (n >= N_NODES) return;
    const unsigned f = flag8[n];
    if (!f) return;
    float o[K];
    int cnt = 0;
    #pragma unroll
    for (int k = 0; k < K; ++k) {
        const float m = mask[(size_t)n * K + k];
        bool hm;
        if ((f >> k) & 1) {
            double b = 0.0;
            for (int j = 0; j < D; ++j)
                b = fma((double)x[(size_t)n * D + j], (double)Wm[k * D + j], b);
            hm = (b + score64[(size_t)n * K + k]) > 0.0;
        } else {
            hm = (m > 0.0f) &&
                 ((base32[(size_t)n * K + k] + agg32[(size_t)n * K + k]) > 0.0f);
        }
        o[k] = (hm && cnt < 2) ? 1.0f : 0.0f;
        cnt += hm ? 1 : 0;
    }
    float4* op = (float4*)(out + (size_t)n * K);
    op[0] = make_float4(o[0], o[1], o[2], o[3]);
    op[1] = make_float4(o[4], o[5], o[6], o[7]);
}

extern "C" void kernel_launch(void* const* d_in, const int* in_sizes, int n_in,
                              void* d_out, int out_size, void* d_ws, size_t ws_size,
                              hipStream_t stream)
{
    const float* x    = (const float*)d_in[0];
    const int*   ei   = (const int*)d_in[1];   // edge_index [2, E] int32
    const float* mask = (const float*)d_in[2]; // [N, K]
    const float* Ww   = (const float*)d_in[3]; // [K, D, D]
    const float* Wm   = (const float*)d_in[4]; // [K, D, 1]
    float* out = (float*)d_out;                // [N, K] float32

    // workspace layout:
    //   [0, 3.2M)            t32      f32[N*K]
    //   [3.2M, 6.4M)         agg32    f32[N*K]
    //   [6.4M, 12.8M)        s64      f64[N*K]  (early: lists int[K][N], 3.2M)
    //   [12.8M, +100000)     flag8    u8[N]
    //   [12,900,000, +32)    cnts     int[8]
    //   [12,900,032, +4)     wlcnt    int
    //   [12,900,040, +2M)    wl       int2[WL_CAP]
    //   [14,997,192, +3.2M)  base32   f32[N*K]          (end ~18.2 MB)
    char* w = (char*)d_ws;
    float*         t32    = (float*)w;
    float*         agg32  = (float*)(w + 3200000);
    double*        s64    = (double*)(w + 6400000);
    int*           lists  = (int*)(w + 6400000);       // overlays s64 (dead then)
    unsigned char* flag8  = (unsigned char*)(w + 12800000);
    int*           cnts   = (int*)(w + 12900000);
    int*           wlcnt  = (int*)(w + 12900032);
    int2*          wl     = (int2*)(w + 12900040);
    float*         b32    = (float*)(w + 12900040 + (size_t)WL_CAP * 8);

    // zero t32|agg32 and flag8|cnts|wlcnt (s64 zeroed later, after gemm)
    hipMemsetAsync(w, 0, 6400000, stream);
    hipMemsetAsync(w + 12800000, 0, 100040, stream);

    compact_kernel<<<(N_NODES + 255) / 256, 256, 0, stream>>>(mask, lists, cnts);

    dim3 g1((N_NODES + CHUNK - 1) / CHUNK, K);
    head_gemm_kernel<<<g1, 256, 0, stream>>>(x, Ww, Wm, lists, cnts, t32, b32);

    const long long nek = (long long)N_EDGES * K;
    scatter_kernel<<<(int)((nek + 255) / 256), 256, 0, stream>>>(ei, t32, agg32);

    combine_flag_kernel<<<(N_NODES + 255) / 256, 256, 0, stream>>>(
        mask, b32, agg32, out, flag8);

    // lists dead now; zero s64 for exact re-accumulation
    hipMemsetAsync(s64, 0, 6400000, stream);

    edge_flag_kernel<<<(N_EDGES + 255) / 256, 256, 0, stream>>>(
        ei, mask, flag8, wl, wlcnt);

    repair_t_kernel<<<512, 256, 0, stream>>>(x, Ww, Wm, wl, wlcnt, s64);

    repair_combine_kernel<<<(N_NODES + 255) / 256, 256, 0, stream>>>(
        x, mask, Wm, b32, agg32, s64, flag8, out);
}